// Round 6
// baseline (163.035 us; speedup 1.0000x reference)
//
#include <hip/hip_runtime.h>

// VQ-VAE forward, K-split bf16 MFMA distance scan.
//   score'(t,c) = dot(x,w) + (0.25 - ||w||^2/2)  in [0.15,0.35] > 0
//   dist = xsq + 0.5 - 2*score' ;  argmax score' == argmin dist
//
// R6: occupancy was grid-capped (131072/64 tok = 2048 waves = 8/CU -> latency
//     bound at ~700 GB/s). Fix: K-split x4 — each block's 4 waves share the
//     same 64 tokens (A-frags) but scan different 256-code quarters;
//     8192 waves total. Scan compares are exact fp32 (cmp+cndmask) — the
//     R4/R5 packed-u32 truncation caused mass false-ties (usage absmax=12).
//     Cross-wave combine via u64 keys at full precision. Relaxed atomics only;
//     coherent final reads via atomicAdd(p,0).
//
// ws: [0,4096) u32 counts[1024] | [4096,4104) double sse | [4104,4108) u32 done
//     [12288,16384) float wnh[1024] (= 0.25 - 0.5||w||^2)
//     [16384,16384+131072) uint4 wbf_sw[8192]  (swizzled bf16 W, read order)

typedef __bf16 bf16x8 __attribute__((ext_vector_type(8)));
typedef float  f32x4  __attribute__((ext_vector_type(4)));

constexpr int D = 64;
constexpr int K = 1024;
constexpr int TOKB = 64;         // tokens per block (shared by all 4 waves)
constexpr float CSHIFT = 0.25f;  // positivity shift: |dot| <= ||x||*||w|| < 0.1

__global__ __launch_bounds__(256) void vq_init(const float* __restrict__ W,
                                               unsigned* __restrict__ counts,
                                               float* __restrict__ wnh,
                                               unsigned* __restrict__ done,
                                               double* __restrict__ sse,
                                               uint4* __restrict__ wbf) {
  const int c = blockIdx.x * 256 + threadIdx.x;  // 0..1023
  const float4* row = reinterpret_cast<const float4*>(W + c * D);
  float s = 0.f;
#pragma unroll
  for (int p = 0; p < 8; ++p) {  // part p = dims p*8..p*8+7
    float4 v0 = row[2 * p], v1 = row[2 * p + 1];
    s = fmaf(v0.x, v0.x, s); s = fmaf(v0.y, v0.y, s);
    s = fmaf(v0.z, v0.z, s); s = fmaf(v0.w, v0.w, s);
    s = fmaf(v1.x, v1.x, s); s = fmaf(v1.y, v1.y, s);
    s = fmaf(v1.z, v1.z, s); s = fmaf(v1.w, v1.w, s);
    bf16x8 pk;
    pk[0] = (__bf16)v0.x; pk[1] = (__bf16)v0.y; pk[2] = (__bf16)v0.z; pk[3] = (__bf16)v0.w;
    pk[4] = (__bf16)v1.x; pk[5] = (__bf16)v1.y; pk[6] = (__bf16)v1.z; pk[7] = (__bf16)v1.w;
    // slot order == exact wave read order in vq_main (tile, half, part, col)
    const int slot = (c >> 4) * 128 + (p >> 2) * 64 + (p & 3) * 16 + (c & 15);
    wbf[slot] = __builtin_bit_cast(uint4, pk);
  }
  wnh[c] = CSHIFT - 0.5f * s;
  counts[c] = 0u;
  if (c == 0) { *sse = 0.0; *done = 0u; }
}

// 256 threads = 4 waves; all waves share 64 tokens, each scans a K-quarter.
__global__ __launch_bounds__(256, 4) void vq_main(const float* __restrict__ x,
                                                  const float* __restrict__ Wf,
                                                  const uint4* __restrict__ wbf,
                                                  const float* __restrict__ wnh,
                                                  unsigned* __restrict__ counts,
                                                  double* __restrict__ sse,
                                                  unsigned* __restrict__ done,
                                                  float* __restrict__ out,
                                                  int nblocks, int n_tokens) {
  __shared__ float s_wnh[K];                        // 4 KB
  __shared__ unsigned long long s_cand[TOKB * 4];   // 2 KB
  __shared__ unsigned s_idx[TOKB];                  // 256 B
  __shared__ double sdd[4];
  __shared__ int sui[4];
  __shared__ unsigned s_lastf;

  const int tid = threadIdx.x;
  const int wv = tid >> 6, lane = tid & 63;
  const int g = lane >> 4, nl = lane & 15;
  const int tokwg = blockIdx.x * TOKB;

  for (int i = tid; i < K; i += 256) s_wnh[i] = wnh[i];

  // A fragments (identical in all 4 waves): lane holds A[m=nl][k=g*8+j].
  bf16x8 afrag[4][2];
  float xsq = 0.f;
#pragma unroll
  for (int tt = 0; tt < 4; ++tt) {
#pragma unroll
    for (int s = 0; s < 2; ++s) {
      const float* px = x + (size_t)(tokwg + tt * 16 + nl) * D + s * 32 + g * 8;
      float4 v0 = *reinterpret_cast<const float4*>(px);
      float4 v1 = *reinterpret_cast<const float4*>(px + 4);
      xsq = fmaf(v0.x, v0.x, xsq); xsq = fmaf(v0.y, v0.y, xsq);
      xsq = fmaf(v0.z, v0.z, xsq); xsq = fmaf(v0.w, v0.w, xsq);
      xsq = fmaf(v1.x, v1.x, xsq); xsq = fmaf(v1.y, v1.y, xsq);
      xsq = fmaf(v1.z, v1.z, xsq); xsq = fmaf(v1.w, v1.w, xsq);
      bf16x8 pk;
      pk[0] = (__bf16)v0.x; pk[1] = (__bf16)v0.y; pk[2] = (__bf16)v0.z; pk[3] = (__bf16)v0.w;
      pk[4] = (__bf16)v1.x; pk[5] = (__bf16)v1.y; pk[6] = (__bf16)v1.z; pk[7] = (__bf16)v1.w;
      afrag[tt][s] = pk;
    }
  }
  __syncthreads();  // s_wnh ready

  float bestv[4][4];
  unsigned bestc[4][4];
#pragma unroll
  for (int tt = 0; tt < 4; ++tt)
#pragma unroll
    for (int j = 0; j < 4; ++j) { bestv[tt][j] = -1.0f; bestc[tt][j] = 0u; }

  // Scan this wave's K-quarter: 16 code-tiles, exact fp32 compares.
#pragma unroll 2
  for (int ct = 0; ct < 16; ++ct) {
    const int cq = wv * 16 + ct;  // global tile id 0..63 (code = cq*16+nl)
    const float w0 = s_wnh[cq * 16 + nl];
    bf16x8 b0 = __builtin_bit_cast(bf16x8, wbf[cq * 128 + lane]);       // dims 0..31
    bf16x8 b1 = __builtin_bit_cast(bf16x8, wbf[cq * 128 + 64 + lane]);  // dims 32..63
#pragma unroll
    for (int tt = 0; tt < 4; ++tt) {
      f32x4 acc = {w0, w0, w0, w0};  // C init = 0.25 - ||w||^2/2
      acc = __builtin_amdgcn_mfma_f32_16x16x32_bf16(afrag[tt][0], b0, acc, 0, 0, 0);
      acc = __builtin_amdgcn_mfma_f32_16x16x32_bf16(afrag[tt][1], b1, acc, 0, 0, 0);
#pragma unroll
      for (int j = 0; j < 4; ++j) {
        const bool m = acc[j] > bestv[tt][j];  // strict > keeps earlier (smaller) code
        bestv[tt][j] = m ? acc[j] : bestv[tt][j];
        bestc[tt][j] = m ? (unsigned)cq : bestc[tt][j];
      }
    }
  }

  // Cross-lane argmax over the 16 cols; C/D row = 4*g+j, col = nl.
#pragma unroll
  for (int tt = 0; tt < 4; ++tt) {
#pragma unroll
    for (int j = 0; j < 4; ++j) {
      float b = bestv[tt][j];
      unsigned c = bestc[tt][j] * 16 + (unsigned)nl;  // full code id
#pragma unroll
      for (int off = 1; off < 16; off <<= 1) {
        float ob = __shfl_xor(b, off, 64);
        unsigned oc = (unsigned)__shfl_xor((int)c, off, 64);
        if (ob > b || (ob == b && oc < c)) { b = ob; c = oc; }
      }
      if (nl == 0) {
        const int tok = tt * 16 + 4 * g + j;  // 0..63
        // scores positive -> float bits monotone; complement code for ties
        s_cand[tok * 4 + wv] =
            ((unsigned long long)__builtin_bit_cast(unsigned, b) << 10) |
            (unsigned long long)(1023u - c);
      }
    }
  }
  __syncthreads();

  // Wave 0 combines the 4 K-quarters per token + accumulates SSE.
  if (tid < 64) {
    const unsigned long long* pc = &s_cand[tid * 4];
    unsigned long long p = pc[0];
    p = p > pc[1] ? p : pc[1];
    p = p > pc[2] ? p : pc[2];
    p = p > pc[3] ? p : pc[3];
    const unsigned ci = 1023u - (unsigned)(p & 1023u);
    s_idx[tid] = ci;
    atomicAdd(&counts[ci], 1u);  // relaxed device-scope
    const float sc = __builtin_bit_cast(float, (unsigned)(p >> 10));
    // lane's xsq slice + this token's (dist - xsq) part; wave-sum = block SSE
    float sv = xsq + fmaf(-2.0f, sc, 0.5f);
#pragma unroll
    for (int off = 32; off > 0; off >>= 1) sv += __shfl_down(sv, off, 64);
    if (tid == 0) atomicAdd(sse, (double)sv);
  }
  if (tid == 0) {
    __builtin_amdgcn_s_waitcnt(0);  // counts+sse atomics (all wave-0 ops) at L2
    unsigned r = __hip_atomic_fetch_add(done, 1u, __ATOMIC_RELAXED,
                                        __HIP_MEMORY_SCOPE_AGENT);
    s_lastf = (r == (unsigned)(nblocks - 1)) ? 1u : 0u;
  }
  __syncthreads();  // publishes s_idx + s_lastf

  // out = W[idx] (fp32 gather; == x + (q-x) to <=1 ulp).
  const int d4 = tid & 15;
#pragma unroll
  for (int tk = 0; tk < 4; ++tk) {
    const int tl = tk * 16 + (tid >> 4);
    const unsigned ci = s_idx[tl];
    float4 q = *reinterpret_cast<const float4*>(Wf + ci * D + d4 * 4);
    *reinterpret_cast<float4*>(out + (size_t)(tokwg + tl) * D + d4 * 4) = q;
  }

  if (s_lastf) {  // last-finishing block: loss / perplexity / usage
    double dsum = 0.0;
    int usum = 0;
    const float inv = 1.0f / (float)n_tokens;
    for (int i = tid; i < K; i += 256) {
      unsigned c = atomicAdd(&counts[i], 0u);  // coherent RMW read
      float pr = (float)c * inv;
      dsum += (double)(pr * logf(pr + 1e-10f));
      usum += (c >= 1u) ? 1 : 0;
    }
#pragma unroll
    for (int off = 32; off > 0; off >>= 1) {
      dsum += __shfl_down(dsum, off, 64);
      usum += __shfl_down(usum, off, 64);
    }
    if (lane == 0) { sdd[wv] = dsum; sui[wv] = usum; }
    __syncthreads();
    if (tid == 0) {
      double s2 = (sdd[0] + sdd[1]) + (sdd[2] + sdd[3]);
      int u2 = (sui[0] + sui[1]) + (sui[2] + sui[3]);
      double svv = atomicAdd(sse, 0.0);  // coherent read (returns old = total)
      double mean = svv / ((double)n_tokens * (double)D);
      float* tail = out + (size_t)n_tokens * D;
      tail[0] = 3.0f * (float)mean;  // q_latent + 2*e_latent
      tail[1] = expf(-(float)s2);    // perplexity
      tail[2] = (float)u2;           // usage
    }
  }
}

extern "C" void kernel_launch(void* const* d_in, const int* in_sizes, int n_in,
                              void* d_out, int out_size, void* d_ws, size_t ws_size,
                              hipStream_t stream) {
  const float* x = (const float*)d_in[0];
  const float* W = (const float*)d_in[1];
  float* out = (float*)d_out;

  unsigned* counts = (unsigned*)d_ws;
  double* sse = (double*)((char*)d_ws + 4096);
  unsigned* done = (unsigned*)((char*)d_ws + 4104);
  float* wnh = (float*)((char*)d_ws + 12288);
  uint4* wbf = (uint4*)((char*)d_ws + 16384);

  const int n_tokens = in_sizes[0] / D;  // 131072
  const int blocks = n_tokens / TOKB;    // 2048

  vq_init<<<K / 256, 256, 0, stream>>>(W, counts, wnh, done, sse, wbf);
  vq_main<<<blocks, 256, 0, stream>>>(x, W, wbf, wnh, counts, sse, done, out,
                                      blocks, n_tokens);
}